// Round 1
// baseline (892.812 us; speedup 1.0000x reference)
//
#include <hip/hip_runtime.h>
#include <math.h>

#define IN_DIM   128
#define OUT_DIM  128
#define EDGE_DIM 32
#define NUM_HEADS 8
#define HEAD_DIM 16
#define SCALE 0.25f

// ---------------------------------------------------------------------------
// Kernel A: reduce We (32x128) -> WeR (32x8) over head_dim, be -> beR (8)
// edge_bias.sum(-1) == ef @ WeR + beR  -- saves a 6.6 GFLOP GEMM.
// ---------------------------------------------------------------------------
__global__ __launch_bounds__(256) void reduce_we_kernel(
    const float* __restrict__ We, const float* __restrict__ be,
    float* __restrict__ WeR, float* __restrict__ beR)
{
    const int t = threadIdx.x;          // 256 threads, 1 block
    const int k = t >> 3;               // 0..31
    const int h = t & 7;                // 0..7
    float s = 0.f;
#pragma unroll
    for (int d = 0; d < HEAD_DIM; ++d) s += We[k * OUT_DIM + h * HEAD_DIM + d];
    WeR[k * NUM_HEADS + h] = s;
    if (t < NUM_HEADS) {
        float sb = 0.f;
#pragma unroll
        for (int d = 0; d < HEAD_DIM; ++d) sb += be[t * HEAD_DIM + d];
        beR[t] = sb;
    }
}

// ---------------------------------------------------------------------------
// Kernel B: fused QKV projection.  grid = (ceil(N/64), 3); block = 256.
// Register-tiled fp32 GEMM: M-tile 64, N = 128, K chunks of 32.
// Thread (tx,ty) in 16x16 grid computes a 4-row x 8-col micro-tile.
// ---------------------------------------------------------------------------
__global__ __launch_bounds__(256) void qkv_kernel(
    const float* __restrict__ X,
    const float* __restrict__ Wq, const float* __restrict__ bq,
    const float* __restrict__ Wk, const float* __restrict__ bk,
    const float* __restrict__ Wv, const float* __restrict__ bv,
    float* __restrict__ Q, float* __restrict__ K, float* __restrict__ V,
    int n_nodes)
{
    const int which = blockIdx.y;
    const float* __restrict__ W = (which == 0) ? Wq : (which == 1) ? Wk : Wv;
    const float* __restrict__ b = (which == 0) ? bq : (which == 1) ? bk : bv;
    float* __restrict__ O       = (which == 0) ? Q  : (which == 1) ? K  : V;

    __shared__ float Xs[32][68];    // X^T tile: [k][m], pad 68 keeps 16B align + breaks conflicts
    __shared__ float Ws[32][132];   // W tile:   [k][j]

    const int t  = threadIdx.x;
    const int tx = t & 15;          // column group: cols tx*8 .. tx*8+7
    const int ty = t >> 4;          // row group:    rows ty*4 .. ty*4+3
    const int m0 = blockIdx.x * 64;

    float acc[4][8];
#pragma unroll
    for (int r = 0; r < 4; ++r)
#pragma unroll
        for (int c = 0; c < 8; ++c) acc[r][c] = 0.f;

    for (int kc = 0; kc < IN_DIM; kc += 32) {
        // stage X tile (transposed): rows m0..m0+63, k in [kc, kc+32)
        {
            const int kk   = (t & 7) * 4;   // 0..28
            int       mrow = t >> 3;        // 0..31, then +32
#pragma unroll
            for (int pass = 0; pass < 2; ++pass, mrow += 32) {
                int gr = m0 + mrow;
                if (gr >= n_nodes) gr = n_nodes - 1;   // clamp: OOB rows masked at store
                const float4 xv = *(const float4*)(X + (size_t)gr * IN_DIM + kc + kk);
                Xs[kk + 0][mrow] = xv.x;
                Xs[kk + 1][mrow] = xv.y;
                Xs[kk + 2][mrow] = xv.z;
                Xs[kk + 3][mrow] = xv.w;
            }
        }
        // stage W tile: [kc..kc+32) x [0..128)
        {
            int idx4 = t;                   // float4 index
#pragma unroll
            for (int rr = 0; rr < 4; ++rr, idx4 += 256) {
                const int kk = idx4 >> 5;          // 0..31
                const int jj = (idx4 & 31) * 4;    // 0..124
                const float4 wv = *(const float4*)(W + (size_t)(kc + kk) * OUT_DIM + jj);
                *(float4*)&Ws[kk][jj] = wv;
            }
        }
        __syncthreads();

#pragma unroll
        for (int k = 0; k < 32; ++k) {
            float av[4], bv8[8];
            *(float4*)av        = *(const float4*)&Xs[k][ty * 4];
            *(float4*)bv8       = *(const float4*)&Ws[k][tx * 8];
            *(float4*)(bv8 + 4) = *(const float4*)&Ws[k][tx * 8 + 4];
#pragma unroll
            for (int r = 0; r < 4; ++r)
#pragma unroll
                for (int c = 0; c < 8; ++c)
                    acc[r][c] = fmaf(av[r], bv8[c], acc[r][c]);
        }
        __syncthreads();
    }

    // epilogue: bias + store
    float bias[8];
#pragma unroll
    for (int c = 0; c < 8; ++c) bias[c] = b[tx * 8 + c];
#pragma unroll
    for (int r = 0; r < 4; ++r) {
        const int gr = m0 + ty * 4 + r;
        if (gr < n_nodes) {
            float o[8];
#pragma unroll
            for (int c = 0; c < 8; ++c) o[c] = acc[r][c] + bias[c];
            float* orow = O + (size_t)gr * OUT_DIM + tx * 8;
            *(float4*)orow       = *(float4*)o;
            *(float4*)(orow + 4) = *(float4*)(o + 4);
        }
    }
}

// ---------------------------------------------------------------------------
// Kernel C: per-edge attention + scatter.  One wave (64 lanes) per edge.
// lane = h*8 + j  (h = head, j = 8-way split of head_dim/edge_dim work)
// ---------------------------------------------------------------------------
__global__ __launch_bounds__(256) void edge_kernel(
    const float* __restrict__ Q, const float* __restrict__ K,
    const float* __restrict__ V,
    const float* __restrict__ ef,          // [E,32]
    const int*   __restrict__ edge_list,   // [E,2]
    const float* __restrict__ WeR,         // [32,8]
    const float* __restrict__ beR,         // [8]
    float* __restrict__ out, int n_edges)
{
    const int e = blockIdx.x * 4 + (threadIdx.x >> 6);
    if (e >= n_edges) return;
    const int lane = threadIdx.x & 63;
    const int h = lane >> 3;
    const int j = lane & 7;

    const int src = edge_list[2 * e];
    const int dst = edge_list[2 * e + 1];

    // QK^T partial: lane covers elements h*16 + 2j, +1  (== float2 index `lane`)
    const float2 q = ((const float2*)(Q + (size_t)src * OUT_DIM))[lane];
    const float2 k = ((const float2*)(K + (size_t)dst * OUT_DIM))[lane];
    float p = SCALE * (q.x * k.x + q.y * k.y);

    // edge-bias partial: ef[e] . WeR[:,h], k-index j, j+8, j+16, j+24
    const float* efe = ef + (size_t)e * EDGE_DIM;
#pragma unroll
    for (int i = 0; i < 4; ++i) {
        const int kidx = j + 8 * i;
        p = fmaf(efe[kidx], WeR[kidx * NUM_HEADS + h], p);
    }

    // reduce over j (lanes sharing h): xor 1,2,4
    p += __shfl_xor(p, 1);
    p += __shfl_xor(p, 2);
    p += __shfl_xor(p, 4);
    const float score = p + beR[h];

    // softmax across heads: xor 8,16,32 butterflies
    float mx = score;
    mx = fmaxf(mx, __shfl_xor(mx, 8));
    mx = fmaxf(mx, __shfl_xor(mx, 16));
    mx = fmaxf(mx, __shfl_xor(mx, 32));
    const float ex = expf(score - mx);
    float den = ex;
    den += __shfl_xor(den, 8);
    den += __shfl_xor(den, 16);
    den += __shfl_xor(den, 32);
    const float w = ex / den;

    // message: V[src] * w scattered to out[dst]
    const float2 v = ((const float2*)(V + (size_t)src * OUT_DIM))[lane];
    float* ob = out + (size_t)dst * OUT_DIM + 2 * lane;
    atomicAdd(ob,     v.x * w);
    atomicAdd(ob + 1, v.y * w);
}

// ---------------------------------------------------------------------------
extern "C" void kernel_launch(void* const* d_in, const int* in_sizes, int n_in,
                              void* d_out, int out_size, void* d_ws, size_t ws_size,
                              hipStream_t stream)
{
    const float* X   = (const float*)d_in[0];
    const float* ef  = (const float*)d_in[1];
    const float* Wq  = (const float*)d_in[2];
    const float* bq  = (const float*)d_in[3];
    const float* Wk  = (const float*)d_in[4];
    const float* bk  = (const float*)d_in[5];
    const float* Wv  = (const float*)d_in[6];
    const float* bv  = (const float*)d_in[7];
    const float* We  = (const float*)d_in[8];
    const float* be  = (const float*)d_in[9];
    const int*   el  = (const int*)d_in[10];

    const int n_nodes = in_sizes[0] / IN_DIM;
    const int n_edges = in_sizes[10] / 2;

    const size_t NM = (size_t)n_nodes * OUT_DIM;
    float* Q   = (float*)d_ws;
    float* K   = Q + NM;
    float* V   = K + NM;
    float* WeR = V + NM;
    float* beR = WeR + EDGE_DIM * NUM_HEADS;

    // out is poisoned 0xAA every call -> zero it (memset node is graph-capturable)
    hipMemsetAsync(d_out, 0, (size_t)out_size * sizeof(float), stream);

    reduce_we_kernel<<<1, 256, 0, stream>>>(We, be, WeR, beR);

    dim3 qkv_grid((n_nodes + 63) / 64, 3);
    qkv_kernel<<<qkv_grid, 256, 0, stream>>>(X, Wq, bq, Wk, bk, Wv, bv, Q, K, V, n_nodes);

    edge_kernel<<<(n_edges + 3) / 4, 256, 0, stream>>>(
        Q, K, V, ef, el, WeR, beR, (float*)d_out, n_edges);
}

// Round 2
// 586.106 us; speedup vs baseline: 1.5233x; 1.5233x over previous
//
#include <hip/hip_runtime.h>
#include <math.h>

#define IN_DIM   128
#define OUT_DIM  128
#define EDGE_DIM 32
#define NUM_HEADS 8
#define HEAD_DIM 16
#define SCALE 0.25f

// ---------------------------------------------------------------------------
// Kernel A: reduce We (32x128) -> WeR (32x8) over head_dim, be -> beR (8)
// edge_bias.sum(-1) == ef @ WeR + beR  -- saves a 6.6 GFLOP GEMM.
// ---------------------------------------------------------------------------
__global__ __launch_bounds__(256) void reduce_we_kernel(
    const float* __restrict__ We, const float* __restrict__ be,
    float* __restrict__ WeR, float* __restrict__ beR)
{
    const int t = threadIdx.x;          // 256 threads, 1 block
    const int k = t >> 3;               // 0..31
    const int h = t & 7;                // 0..7
    float s = 0.f;
#pragma unroll
    for (int d = 0; d < HEAD_DIM; ++d) s += We[k * OUT_DIM + h * HEAD_DIM + d];
    WeR[k * NUM_HEADS + h] = s;
    if (t < NUM_HEADS) {
        float sb = 0.f;
#pragma unroll
        for (int d = 0; d < HEAD_DIM; ++d) sb += be[t * HEAD_DIM + d];
        beR[t] = sb;
    }
}

// ---------------------------------------------------------------------------
// Kernel B: fused QKV projection (unchanged from R1; profile next round).
// ---------------------------------------------------------------------------
__global__ __launch_bounds__(256) void qkv_kernel(
    const float* __restrict__ X,
    const float* __restrict__ Wq, const float* __restrict__ bq,
    const float* __restrict__ Wk, const float* __restrict__ bk,
    const float* __restrict__ Wv, const float* __restrict__ bv,
    float* __restrict__ Q, float* __restrict__ K, float* __restrict__ V,
    int n_nodes)
{
    const int which = blockIdx.y;
    const float* __restrict__ W = (which == 0) ? Wq : (which == 1) ? Wk : Wv;
    const float* __restrict__ b = (which == 0) ? bq : (which == 1) ? bk : bv;
    float* __restrict__ O       = (which == 0) ? Q  : (which == 1) ? K  : V;

    __shared__ float Xs[32][68];
    __shared__ float Ws[32][132];

    const int t  = threadIdx.x;
    const int tx = t & 15;
    const int ty = t >> 4;
    const int m0 = blockIdx.x * 64;

    float acc[4][8];
#pragma unroll
    for (int r = 0; r < 4; ++r)
#pragma unroll
        for (int c = 0; c < 8; ++c) acc[r][c] = 0.f;

    for (int kc = 0; kc < IN_DIM; kc += 32) {
        {
            const int kk   = (t & 7) * 4;
            int       mrow = t >> 3;
#pragma unroll
            for (int pass = 0; pass < 2; ++pass, mrow += 32) {
                int gr = m0 + mrow;
                if (gr >= n_nodes) gr = n_nodes - 1;
                const float4 xv = *(const float4*)(X + (size_t)gr * IN_DIM + kc + kk);
                Xs[kk + 0][mrow] = xv.x;
                Xs[kk + 1][mrow] = xv.y;
                Xs[kk + 2][mrow] = xv.z;
                Xs[kk + 3][mrow] = xv.w;
            }
        }
        {
            int idx4 = t;
#pragma unroll
            for (int rr = 0; rr < 4; ++rr, idx4 += 256) {
                const int kk = idx4 >> 5;
                const int jj = (idx4 & 31) * 4;
                const float4 wv = *(const float4*)(W + (size_t)(kc + kk) * OUT_DIM + jj);
                *(float4*)&Ws[kk][jj] = wv;
            }
        }
        __syncthreads();

#pragma unroll
        for (int k = 0; k < 32; ++k) {
            float av[4], bv8[8];
            *(float4*)av        = *(const float4*)&Xs[k][ty * 4];
            *(float4*)bv8       = *(const float4*)&Ws[k][tx * 8];
            *(float4*)(bv8 + 4) = *(const float4*)&Ws[k][tx * 8 + 4];
#pragma unroll
            for (int r = 0; r < 4; ++r)
#pragma unroll
                for (int c = 0; c < 8; ++c)
                    acc[r][c] = fmaf(av[r], bv8[c], acc[r][c]);
        }
        __syncthreads();
    }

    float bias[8];
#pragma unroll
    for (int c = 0; c < 8; ++c) bias[c] = b[tx * 8 + c];
#pragma unroll
    for (int r = 0; r < 4; ++r) {
        const int gr = m0 + ty * 4 + r;
        if (gr < n_nodes) {
            float o[8];
#pragma unroll
            for (int c = 0; c < 8; ++c) o[c] = acc[r][c] + bias[c];
            float* orow = O + (size_t)gr * OUT_DIM + tx * 8;
            *(float4*)orow       = *(float4*)o;
            *(float4*)(orow + 4) = *(float4*)(o + 4);
        }
    }
}

// ---------------------------------------------------------------------------
// Counting sort of edges by dst: histogram -> scan -> scatter
// ---------------------------------------------------------------------------
__global__ __launch_bounds__(256) void hist_kernel(
    const int* __restrict__ el, int* __restrict__ counts, int n_edges)
{
    const int e = blockIdx.x * 256 + threadIdx.x;
    if (e < n_edges) atomicAdd(&counts[el[2 * e + 1]], 1);
}

__global__ __launch_bounds__(1024) void scan_kernel(
    const int* __restrict__ counts, int* __restrict__ offsets,
    int* __restrict__ cursor, int n, int n_edges)
{
    __shared__ int lds[1024];
    const int t = threadIdx.x;
    const int c = (n + 1023) >> 10;
    const int base = t * c;
    const int lim  = min(base + c, n);
    int s = 0;
    for (int i = base; i < lim; ++i) s += counts[i];
    lds[t] = s;
    __syncthreads();
    for (int off = 1; off < 1024; off <<= 1) {
        int v = (t >= off) ? lds[t - off] : 0;
        __syncthreads();
        lds[t] += v;
        __syncthreads();
    }
    int run = (t > 0) ? lds[t - 1] : 0;
    for (int i = base; i < lim; ++i) {
        offsets[i] = run;
        cursor[i]  = run;
        run += counts[i];
    }
    if (t == 1023) offsets[n] = n_edges;
}

// scatter: place src ids + precomputed per-edge head bias into dst-sorted order
__global__ __launch_bounds__(256) void scatter_kernel(
    const int* __restrict__ el, const float* __restrict__ ef,
    const float* __restrict__ WeR, const float* __restrict__ beR,
    int* __restrict__ cursor, int* __restrict__ srcs,
    float* __restrict__ ebias, int n_edges)
{
    __shared__ float WeRs[EDGE_DIM * NUM_HEADS];
    __shared__ float beRs[NUM_HEADS];
    const int t = threadIdx.x;
    WeRs[t] = WeR[t];
    if (t < NUM_HEADS) beRs[t] = beR[t];
    __syncthreads();

    const int e = blockIdx.x * 256 + t;
    if (e >= n_edges) return;
    const int src = el[2 * e];
    const int dst = el[2 * e + 1];

    float acc[NUM_HEADS];
#pragma unroll
    for (int h = 0; h < NUM_HEADS; ++h) acc[h] = beRs[h];

    const float4* efr = (const float4*)(ef + (size_t)e * EDGE_DIM);
#pragma unroll
    for (int kk = 0; kk < 8; ++kk) {
        const float4 f = efr[kk];
        const float* w0 = &WeRs[(kk * 4 + 0) * NUM_HEADS];
        const float* w1 = &WeRs[(kk * 4 + 1) * NUM_HEADS];
        const float* w2 = &WeRs[(kk * 4 + 2) * NUM_HEADS];
        const float* w3 = &WeRs[(kk * 4 + 3) * NUM_HEADS];
#pragma unroll
        for (int h = 0; h < NUM_HEADS; ++h)
            acc[h] = fmaf(f.x, w0[h], fmaf(f.y, w1[h], fmaf(f.z, w2[h], fmaf(f.w, w3[h], acc[h]))));
    }

    const int pos = atomicAdd(&cursor[dst], 1);
    srcs[pos] = src;
    float4* eb = (float4*)(ebias + (size_t)pos * NUM_HEADS);
    eb[0] = make_float4(acc[0], acc[1], acc[2], acc[3]);
    eb[1] = make_float4(acc[4], acc[5], acc[6], acc[7]);
}

// ---------------------------------------------------------------------------
// Kernel C: per-dst aggregation. One wave per dst node; K[dst] in regs;
// per edge: gather Q/V[src] (prefetched), shuffle QK-reduce + head softmax,
// accumulate in regs; single coalesced 512B store. Zero output atomics.
// ---------------------------------------------------------------------------
__global__ __launch_bounds__(256) void aggregate_kernel(
    const float* __restrict__ Q, const float* __restrict__ K,
    const float* __restrict__ V,
    const int* __restrict__ offsets, const int* __restrict__ srcs,
    const float* __restrict__ ebias,
    float* __restrict__ out, int n_nodes)
{
    const int wid  = (blockIdx.x * 256 + threadIdx.x) >> 6;   // global wave = dst node
    const int lane = threadIdx.x & 63;
    if (wid >= n_nodes) return;
    const int h = lane >> 3;

    const int beg = offsets[wid];
    const int end = offsets[wid + 1];

    const float2 k2 = ((const float2*)(K + (size_t)wid * OUT_DIM))[lane];
    float accx = 0.f, accy = 0.f;

    float2 q2, v2;
    float  eb = 0.f;
    if (beg < end) {
        const int src = srcs[beg];
        q2 = ((const float2*)(Q + (size_t)src * OUT_DIM))[lane];
        v2 = ((const float2*)(V + (size_t)src * OUT_DIM))[lane];
        eb = ebias[(size_t)beg * NUM_HEADS + h];
    }

    for (int i = beg; i < end; ++i) {
        float2 nq = q2, nv = v2;
        float  neb = eb;
        if (i + 1 < end) {  // prefetch next edge while current chain resolves
            const int nsrc = srcs[i + 1];
            nq  = ((const float2*)(Q + (size_t)nsrc * OUT_DIM))[lane];
            nv  = ((const float2*)(V + (size_t)nsrc * OUT_DIM))[lane];
            neb = ebias[(size_t)(i + 1) * NUM_HEADS + h];
        }

        float p = q2.x * k2.x + q2.y * k2.y;
        p += __shfl_xor(p, 1);
        p += __shfl_xor(p, 2);
        p += __shfl_xor(p, 4);
        const float score = p * SCALE + eb;

        float mx = score;
        mx = fmaxf(mx, __shfl_xor(mx, 8));
        mx = fmaxf(mx, __shfl_xor(mx, 16));
        mx = fmaxf(mx, __shfl_xor(mx, 32));
        const float ex = __expf(score - mx);
        float den = ex;
        den += __shfl_xor(den, 8);
        den += __shfl_xor(den, 16);
        den += __shfl_xor(den, 32);
        const float w = __fdividef(ex, den);

        accx = fmaf(w, v2.x, accx);
        accy = fmaf(w, v2.y, accy);

        q2 = nq; v2 = nv; eb = neb;
    }

    ((float2*)(out + (size_t)wid * OUT_DIM))[lane] = make_float2(accx, accy);
}

// ---------------------------------------------------------------------------
extern "C" void kernel_launch(void* const* d_in, const int* in_sizes, int n_in,
                              void* d_out, int out_size, void* d_ws, size_t ws_size,
                              hipStream_t stream)
{
    const float* X   = (const float*)d_in[0];
    const float* ef  = (const float*)d_in[1];
    const float* Wq  = (const float*)d_in[2];
    const float* bq  = (const float*)d_in[3];
    const float* Wk  = (const float*)d_in[4];
    const float* bk  = (const float*)d_in[5];
    const float* Wv  = (const float*)d_in[6];
    const float* bv  = (const float*)d_in[7];
    const float* We  = (const float*)d_in[8];
    const float* be  = (const float*)d_in[9];
    const int*   el  = (const int*)d_in[10];

    const int n_nodes = in_sizes[0] / IN_DIM;
    const int n_edges = in_sizes[10] / 2;

    const size_t NM = (size_t)n_nodes * OUT_DIM;

    // float workspace
    float* Q     = (float*)d_ws;
    float* K     = Q + NM;
    float* V     = K + NM;
    float* ebias = V + NM;                         // E*8 floats, 16B-aligned
    float* WeR   = ebias + (size_t)n_edges * NUM_HEADS;
    float* beR   = WeR + EDGE_DIM * NUM_HEADS;
    // int workspace
    int* counts  = (int*)(beR + NUM_HEADS);
    int* offsets = counts + n_nodes;               // n_nodes+1
    int* cursor  = offsets + n_nodes + 1;
    int* srcs    = cursor + n_nodes;

    hipMemsetAsync(counts, 0, (size_t)n_nodes * sizeof(int), stream);

    reduce_we_kernel<<<1, 256, 0, stream>>>(We, be, WeR, beR);

    dim3 qkv_grid((n_nodes + 63) / 64, 3);
    qkv_kernel<<<qkv_grid, 256, 0, stream>>>(X, Wq, bq, Wk, bk, Wv, bv, Q, K, V, n_nodes);

    hist_kernel<<<(n_edges + 255) / 256, 256, 0, stream>>>(el, counts, n_edges);
    scan_kernel<<<1, 1024, 0, stream>>>(counts, offsets, cursor, n_nodes, n_edges);
    scatter_kernel<<<(n_edges + 255) / 256, 256, 0, stream>>>(
        el, ef, WeR, beR, cursor, srcs, ebias, n_edges);

    aggregate_kernel<<<((size_t)n_nodes * 64 + 255) / 256, 256, 0, stream>>>(
        Q, K, V, offsets, srcs, ebias, (float*)d_out, n_nodes);
}

// Round 3
// 418.644 us; speedup vs baseline: 2.1326x; 1.4000x over previous
//
#include <hip/hip_runtime.h>
#include <math.h>

#define IN_DIM   128
#define OUT_DIM  128
#define EDGE_DIM 32
#define NUM_HEADS 8
#define HEAD_DIM 16
#define SCALE 0.25f
#define WPAD 136   // 128 + 8 bf16 pad: row stride 272B -> 2-way LDS conflict (free)

typedef __attribute__((ext_vector_type(8))) short bf16x8;
typedef __attribute__((ext_vector_type(4))) float f32x4;

__device__ inline unsigned short f2bf(float x) {   // round-to-nearest-even
    unsigned int u = __float_as_uint(x);
    unsigned int r = u + 0x7fff + ((u >> 16) & 1);
    return (unsigned short)(r >> 16);
}

// ---------------------------------------------------------------------------
// We (32x128) -> WeR (32x8) head-sum; be -> beR (8).
// ---------------------------------------------------------------------------
__global__ __launch_bounds__(256) void reduce_we_kernel(
    const float* __restrict__ We, const float* __restrict__ be,
    float* __restrict__ WeR, float* __restrict__ beR)
{
    const int t = threadIdx.x;
    const int k = t >> 3;
    const int h = t & 7;
    float s = 0.f;
#pragma unroll
    for (int d = 0; d < HEAD_DIM; ++d) s += We[k * OUT_DIM + h * HEAD_DIM + d];
    WeR[k * NUM_HEADS + h] = s;
    if (t < NUM_HEADS) {
        float sb = 0.f;
#pragma unroll
        for (int d = 0; d < HEAD_DIM; ++d) sb += be[t * HEAD_DIM + d];
        beR[t] = sb;
    }
}

// ---------------------------------------------------------------------------
// fp32 -> bf16 conversions
// ---------------------------------------------------------------------------
__global__ __launch_bounds__(256) void convert_x_kernel(
    const float* __restrict__ X, unsigned short* __restrict__ Xb, int n4)
{
    const int i = blockIdx.x * 256 + threadIdx.x;
    if (i < n4) {
        const float4 v = ((const float4*)X)[i];
        unsigned int lo = (unsigned int)f2bf(v.x) | ((unsigned int)f2bf(v.y) << 16);
        unsigned int hi = (unsigned int)f2bf(v.z) | ((unsigned int)f2bf(v.w) << 16);
        ((uint2*)Xb)[i] = make_uint2(lo, hi);
    }
}

// W[k][n] -> WtB[mat][n][k] (bf16, padded rows)
__global__ __launch_bounds__(256) void convert_w_kernel(
    const float* __restrict__ Wq, const float* __restrict__ Wk,
    const float* __restrict__ Wv, unsigned short* __restrict__ WtB)
{
    const int idx = blockIdx.x * 256 + threadIdx.x;   // 0..49151
    if (idx >= 3 * 128 * 128) return;
    const int mat = idx >> 14;
    const int rem = idx & 16383;
    const int n = rem >> 7, k = rem & 127;
    const float* W = (mat == 0) ? Wq : (mat == 1) ? Wk : Wv;
    WtB[(size_t)mat * 128 * WPAD + n * WPAD + k] = f2bf(W[k * 128 + n]);
}

// ---------------------------------------------------------------------------
// QKV projection via bf16 MFMA.  grid = (ceil(N/64), 3), block = 256 (4 waves).
// Wave w: rows m0+16w..+15, all 128 cols.  K=128 in 4 steps of 32.
// Outputs: Q,V interleaved per node into QVb[node][256]; K into Kb[node][128].
// ---------------------------------------------------------------------------
__global__ __launch_bounds__(256) void qkv_mfma_kernel(
    const unsigned short* __restrict__ Xb,     // [N][128] bf16
    const unsigned short* __restrict__ WtB,    // [3][128][WPAD] bf16 (W^T)
    const float* __restrict__ bq, const float* __restrict__ bk,
    const float* __restrict__ bv,
    unsigned short* __restrict__ QVb,          // [N][256] = Q|V
    unsigned short* __restrict__ Kb,           // [N][128]
    int n_nodes)
{
    __shared__ unsigned short Ws[128][WPAD];        // W^T tile: [n][k]
    __shared__ float bs[128];
    __shared__ unsigned short stg[4][16][WPAD];     // per-wave store staging

    const int t = threadIdx.x;
    const int which = blockIdx.y;   // 0=Q, 1=K, 2=V
    const float* bias = (which == 0) ? bq : (which == 1) ? bk : bv;
    const unsigned short* Wg = WtB + (size_t)which * 128 * WPAD;

    // stage W^T -> LDS: thread t copies 128B (row t>>1, half t&1)
    {
        const int row = t >> 1, half = t & 1;
        const uint4* src = (const uint4*)(Wg + row * WPAD + half * 64);
        uint4* dst = (uint4*)(&Ws[row][half * 64]);
#pragma unroll
        for (int i = 0; i < 8; ++i) dst[i] = src[i];
    }
    if (t < 128) bs[t] = bias[t];
    __syncthreads();

    const int wave = t >> 6, lane = t & 63;
    const int quad = lane >> 4, li = lane & 15;
    const int m0 = blockIdx.x * 64 + wave * 16;
    int mrow = m0 + li;
    if (mrow >= n_nodes) mrow = n_nodes - 1;   // clamp; stores guarded

    f32x4 acc[8];
#pragma unroll
    for (int nt = 0; nt < 8; ++nt) acc[nt] = (f32x4){0.f, 0.f, 0.f, 0.f};

#pragma unroll
    for (int ks = 0; ks < 4; ++ks) {
        const bf16x8 a = *(const bf16x8*)(Xb + (size_t)mrow * 128 + ks * 32 + quad * 8);
#pragma unroll
        for (int nt = 0; nt < 8; ++nt) {
            const bf16x8 b = *(const bf16x8*)(&Ws[nt * 16 + li][ks * 32 + quad * 8]);
            acc[nt] = __builtin_amdgcn_mfma_f32_16x16x32_bf16(a, b, acc[nt], 0, 0, 0);
        }
    }

    // bias + pack to bf16 into staging (D: row = quad*4+r, col = nt*16+li)
#pragma unroll
    for (int nt = 0; nt < 8; ++nt) {
        const float bb = bs[nt * 16 + li];
#pragma unroll
        for (int r = 0; r < 4; ++r)
            stg[wave][quad * 4 + r][nt * 16 + li] = f2bf(acc[nt][r] + bb);
    }
    __syncthreads();   // cross-lane LDS visibility

    // readback: 4 lanes per row, 64B each; coalesced vec stores
    {
        const int R = lane >> 2;      // row in tile
        const int c = lane & 3;       // 64B chunk
        const int node = m0 + R;
        if (node < n_nodes) {
            const uint4* s = (const uint4*)(&stg[wave][R][c * 32]);
            uint4 d0 = s[0], d1 = s[1], d2 = s[2], d3 = s[3];
            unsigned short* dp =
                (which == 0) ? (QVb + (size_t)node * 256 + c * 32)
              : (which == 1) ? (Kb  + (size_t)node * 128 + c * 32)
              :                (QVb + (size_t)node * 256 + 128 + c * 32);
            uint4* d = (uint4*)dp;
            d[0] = d0; d[1] = d1; d[2] = d2; d[3] = d3;
        }
    }
}

// ---------------------------------------------------------------------------
// Counting sort of edges by dst: hist -> 3-phase parallel scan -> scatter
// ---------------------------------------------------------------------------
__global__ __launch_bounds__(256) void hist_kernel(
    const int* __restrict__ el, int* __restrict__ counts, int n_edges)
{
    const int e = blockIdx.x * 256 + threadIdx.x;
    if (e < n_edges) atomicAdd(&counts[el[2 * e + 1]], 1);
}

__global__ __launch_bounds__(256) void scan1_kernel(
    const int* __restrict__ counts, int* __restrict__ bsums, int n)
{
    __shared__ int lds[256];
    const int i = blockIdx.x * 256 + threadIdx.x;
    lds[threadIdx.x] = (i < n) ? counts[i] : 0;
    __syncthreads();
    for (int off = 128; off > 0; off >>= 1) {
        if (threadIdx.x < off) lds[threadIdx.x] += lds[threadIdx.x + off];
        __syncthreads();
    }
    if (threadIdx.x == 0) bsums[blockIdx.x] = lds[0];
}

__global__ __launch_bounds__(256) void scan2_kernel(int* __restrict__ bsums, int nb)
{
    __shared__ int lds[256];
    const int t = threadIdx.x;
    const int v = (t < nb) ? bsums[t] : 0;
    lds[t] = v;
    __syncthreads();
    for (int off = 1; off < 256; off <<= 1) {
        const int u = (t >= off) ? lds[t - off] : 0;
        __syncthreads();
        lds[t] += u;
        __syncthreads();
    }
    if (t < nb) bsums[t] = lds[t] - v;   // exclusive
}

__global__ __launch_bounds__(256) void scan3_kernel(
    const int* __restrict__ counts, const int* __restrict__ bsums,
    int* __restrict__ offsets, int* __restrict__ cursor, int n, int n_edges)
{
    __shared__ int lds[256];
    const int t = threadIdx.x;
    const int i = blockIdx.x * 256 + t;
    const int v = (i < n) ? counts[i] : 0;
    lds[t] = v;
    __syncthreads();
    for (int off = 1; off < 256; off <<= 1) {
        const int u = (t >= off) ? lds[t - off] : 0;
        __syncthreads();
        lds[t] += u;
        __syncthreads();
    }
    if (i < n) {
        const int excl = bsums[blockIdx.x] + lds[t] - v;
        offsets[i] = excl;
        cursor[i]  = excl;
    }
    if (blockIdx.x == 0 && t == 0) offsets[n] = n_edges;
}

// scatter: src ids + precomputed per-edge 8-head bias into dst-sorted order
__global__ __launch_bounds__(256) void scatter_kernel(
    const int* __restrict__ el, const float* __restrict__ ef,
    const float* __restrict__ WeR, const float* __restrict__ beR,
    int* __restrict__ cursor, int* __restrict__ srcs,
    float* __restrict__ ebias, int n_edges)
{
    __shared__ float WeRs[EDGE_DIM * NUM_HEADS];
    __shared__ float beRs[NUM_HEADS];
    const int t = threadIdx.x;
    WeRs[t] = WeR[t];
    if (t < NUM_HEADS) beRs[t] = beR[t];
    __syncthreads();

    const int e = blockIdx.x * 256 + t;
    if (e >= n_edges) return;
    const int src = el[2 * e];
    const int dst = el[2 * e + 1];

    float acc[NUM_HEADS];
#pragma unroll
    for (int h = 0; h < NUM_HEADS; ++h) acc[h] = beRs[h];

    const float4* efr = (const float4*)(ef + (size_t)e * EDGE_DIM);
#pragma unroll
    for (int kk = 0; kk < 8; ++kk) {
        const float4 f = efr[kk];
        const float* w0 = &WeRs[(kk * 4 + 0) * NUM_HEADS];
        const float* w1 = &WeRs[(kk * 4 + 1) * NUM_HEADS];
        const float* w2 = &WeRs[(kk * 4 + 2) * NUM_HEADS];
        const float* w3 = &WeRs[(kk * 4 + 3) * NUM_HEADS];
#pragma unroll
        for (int h = 0; h < NUM_HEADS; ++h)
            acc[h] = fmaf(f.x, w0[h], fmaf(f.y, w1[h], fmaf(f.z, w2[h], fmaf(f.w, w3[h], acc[h]))));
    }

    const int pos = atomicAdd(&cursor[dst], 1);
    srcs[pos] = src;
    float4* eb = (float4*)(ebias + (size_t)pos * NUM_HEADS);
    eb[0] = make_float4(acc[0], acc[1], acc[2], acc[3]);
    eb[1] = make_float4(acc[4], acc[5], acc[6], acc[7]);
}

// ---------------------------------------------------------------------------
// Per-dst aggregation. One wave per dst node; K[dst] in regs (bf16->f32);
// per edge: one 512B QV-row gather (prefetched), shuffle QK + head softmax,
// register accumulate; single coalesced store.
// ---------------------------------------------------------------------------
__global__ __launch_bounds__(256) void aggregate_kernel(
    const unsigned short* __restrict__ QVb, const unsigned short* __restrict__ Kb,
    const int* __restrict__ offsets, const int* __restrict__ srcs,
    const float* __restrict__ ebias,
    float* __restrict__ out, int n_nodes)
{
    const int wid  = (blockIdx.x * 256 + threadIdx.x) >> 6;
    const int lane = threadIdx.x & 63;
    if (wid >= n_nodes) return;
    const int h = lane >> 3;

    const unsigned int kp = ((const unsigned int*)(Kb + (size_t)wid * 128))[lane];
    const float kx = __uint_as_float(kp << 16);
    const float ky = __uint_as_float(kp & 0xffff0000u);

    const int beg = offsets[wid];
    const int end = offsets[wid + 1];
    float accx = 0.f, accy = 0.f;

    unsigned int qp = 0, vp = 0;
    float eb = 0.f;
    if (beg < end) {
        const int src = srcs[beg];
        const unsigned int* r = (const unsigned int*)(QVb + (size_t)src * 256);
        qp = r[lane];
        vp = r[64 + lane];
        eb = ebias[(size_t)beg * NUM_HEADS + h];
    }

    for (int i = beg; i < end; ++i) {
        unsigned int nqp = qp, nvp = vp;
        float neb = eb;
        if (i + 1 < end) {   // prefetch next edge
            const int ns = srcs[i + 1];
            const unsigned int* r = (const unsigned int*)(QVb + (size_t)ns * 256);
            nqp = r[lane];
            nvp = r[64 + lane];
            neb = ebias[(size_t)(i + 1) * NUM_HEADS + h];
        }

        const float qx = __uint_as_float(qp << 16);
        const float qy = __uint_as_float(qp & 0xffff0000u);
        float p = qx * kx + qy * ky;
        p += __shfl_xor(p, 1);
        p += __shfl_xor(p, 2);
        p += __shfl_xor(p, 4);
        const float score = p * SCALE + eb;

        float mx = score;
        mx = fmaxf(mx, __shfl_xor(mx, 8));
        mx = fmaxf(mx, __shfl_xor(mx, 16));
        mx = fmaxf(mx, __shfl_xor(mx, 32));
        const float ex = __expf(score - mx);
        float den = ex;
        den += __shfl_xor(den, 8);
        den += __shfl_xor(den, 16);
        den += __shfl_xor(den, 32);
        const float w = __fdividef(ex, den);

        const float vx = __uint_as_float(vp << 16);
        const float vy = __uint_as_float(vp & 0xffff0000u);
        accx = fmaf(w, vx, accx);
        accy = fmaf(w, vy, accy);

        qp = nqp; vp = nvp; eb = neb;
    }

    ((float2*)(out + (size_t)wid * OUT_DIM))[lane] = make_float2(accx, accy);
}

// ---------------------------------------------------------------------------
extern "C" void kernel_launch(void* const* d_in, const int* in_sizes, int n_in,
                              void* d_out, int out_size, void* d_ws, size_t ws_size,
                              hipStream_t stream)
{
    const float* X   = (const float*)d_in[0];
    const float* ef  = (const float*)d_in[1];
    const float* Wq  = (const float*)d_in[2];
    const float* bq  = (const float*)d_in[3];
    const float* Wk  = (const float*)d_in[4];
    const float* bk  = (const float*)d_in[5];
    const float* Wv  = (const float*)d_in[6];
    const float* bv  = (const float*)d_in[7];
    const float* We  = (const float*)d_in[8];
    const float* be  = (const float*)d_in[9];
    const int*   el  = (const int*)d_in[10];

    const int n_nodes = in_sizes[0] / IN_DIM;
    const int n_edges = in_sizes[10] / 2;

    // workspace carve-up (256B-aligned chunks)
    char* w = (char*)d_ws;
    auto alloc = [&](size_t bytes) { char* p = w; w += (bytes + 255) & ~(size_t)255; return p; };

    unsigned short* QVb = (unsigned short*)alloc((size_t)n_nodes * 256 * 2);
    unsigned short* Kb  = (unsigned short*)alloc((size_t)n_nodes * 128 * 2);
    unsigned short* Xb  = (unsigned short*)alloc((size_t)n_nodes * 128 * 2);
    unsigned short* WtB = (unsigned short*)alloc((size_t)3 * 128 * WPAD * 2);
    float* ebias = (float*)alloc((size_t)n_edges * NUM_HEADS * 4);
    float* WeR   = (float*)alloc(EDGE_DIM * NUM_HEADS * 4);
    float* beR   = (float*)alloc(NUM_HEADS * 4);
    int* counts  = (int*)alloc((size_t)n_nodes * 4);
    int* offsets = (int*)alloc((size_t)(n_nodes + 1) * 4);
    int* cursor  = (int*)alloc((size_t)n_nodes * 4);
    int* srcs    = (int*)alloc((size_t)n_edges * 4);
    int* bsums   = (int*)alloc(256 * 4);

    hipMemsetAsync(counts, 0, (size_t)n_nodes * sizeof(int), stream);

    reduce_we_kernel<<<1, 256, 0, stream>>>(We, be, WeR, beR);

    const int n4 = n_nodes * IN_DIM / 4;
    convert_x_kernel<<<(n4 + 255) / 256, 256, 0, stream>>>(X, Xb, n4);
    convert_w_kernel<<<(3 * 128 * 128 + 255) / 256, 256, 0, stream>>>(Wq, Wk, Wv, WtB);

    dim3 qkv_grid((n_nodes + 63) / 64, 3);
    qkv_mfma_kernel<<<qkv_grid, 256, 0, stream>>>(Xb, WtB, bq, bk, bv, QVb, Kb, n_nodes);

    hist_kernel<<<(n_edges + 255) / 256, 256, 0, stream>>>(el, counts, n_edges);
    const int nb = (n_nodes + 255) / 256;
    scan1_kernel<<<nb, 256, 0, stream>>>(counts, bsums, n_nodes);
    scan2_kernel<<<1, 256, 0, stream>>>(bsums, nb);
    scan3_kernel<<<nb, 256, 0, stream>>>(counts, bsums, offsets, cursor, n_nodes, n_edges);

    scatter_kernel<<<(n_edges + 255) / 256, 256, 0, stream>>>(
        el, ef, WeR, beR, cursor, srcs, ebias, n_edges);

    aggregate_kernel<<<((size_t)n_nodes * 64 + 255) / 256, 256, 0, stream>>>(
        QVb, Kb, offsets, srcs, ebias, (float*)d_out, n_nodes);
}

// Round 4
// 418.381 us; speedup vs baseline: 2.1340x; 1.0006x over previous
//
#include <hip/hip_runtime.h>
#include <math.h>

#define IN_DIM   128
#define OUT_DIM  128
#define EDGE_DIM 32
#define NUM_HEADS 8
#define HEAD_DIM 16
#define SCALE 0.25f

typedef __attribute__((ext_vector_type(8))) short bf16x8;
typedef __attribute__((ext_vector_type(4))) float f32x4;

__device__ inline unsigned short f2bf(float x) {   // round-to-nearest-even
    unsigned int u = __float_as_uint(x);
    unsigned int r = u + 0x7fff + ((u >> 16) & 1);
    return (unsigned short)(r >> 16);
}
__device__ inline float bflo(unsigned int u) { return __uint_as_float(u << 16); }
__device__ inline float bfhi(unsigned int u) { return __uint_as_float(u & 0xffff0000u); }

// ---------------------------------------------------------------------------
// prep: fused  [hist over dst] + [W^T bf16 convert] + [We head-sum reduce]
// grid = nbh + nbw + 1 blocks of 256.
// ---------------------------------------------------------------------------
__global__ __launch_bounds__(256) void prep_kernel(
    const int* __restrict__ el, int* __restrict__ counts, int n_edges, int nbh,
    const float* __restrict__ Wq, const float* __restrict__ Wk,
    const float* __restrict__ Wv, unsigned short* __restrict__ WtB, int nbw,
    const float* __restrict__ We, const float* __restrict__ be,
    float* __restrict__ WeR, float* __restrict__ beR)
{
    const int bx = blockIdx.x;
    const int t  = threadIdx.x;
    if (bx < nbh) {                                   // histogram of dst
        const int e = bx * 256 + t;
        if (e < n_edges) atomicAdd(&counts[((const int2*)el)[e].y], 1);
    } else if (bx < nbh + nbw) {                      // W[k][n] -> WtB[mat][n][k]
        const int idx = (bx - nbh) * 256 + t;         // 0..49151
        const int mat = idx >> 14;
        const int rem = idx & 16383;
        const int n = rem >> 7, k = rem & 127;
        const float* W = (mat == 0) ? Wq : (mat == 1) ? Wk : Wv;
        WtB[mat * 16384 + n * 128 + k] = f2bf(W[k * 128 + n]);
    } else {                                          // We reduce
        const int k = t >> 3, h = t & 7;
        float s = 0.f;
#pragma unroll
        for (int d = 0; d < HEAD_DIM; ++d) s += We[k * OUT_DIM + h * HEAD_DIM + d];
        WeR[k * NUM_HEADS + h] = s;
        if (t < NUM_HEADS) {
            float sb = 0.f;
#pragma unroll
            for (int d = 0; d < HEAD_DIM; ++d) sb += be[t * HEAD_DIM + d];
            beR[t] = sb;
        }
    }
}

// ---------------------------------------------------------------------------
// QKV via bf16 MFMA, X converted inline, B-frags straight from global (L2-hot).
// grid = (ceil(N/64), 3), block = 256 (4 waves, 16 rows each).
// ---------------------------------------------------------------------------
__global__ __launch_bounds__(256) void qkv_mfma_kernel(
    const float* __restrict__ X,               // [N][128] fp32
    const unsigned short* __restrict__ WtB,    // [3][128][128] bf16 (W^T)
    const float* __restrict__ bq, const float* __restrict__ bk,
    const float* __restrict__ bv,
    unsigned short* __restrict__ QVb,          // [N][256] = Q|V bf16
    unsigned short* __restrict__ Kb,           // [N][128] bf16
    int n_nodes)
{
    __shared__ unsigned short stg[4][16][136];   // store-staging, +8 pad

    const int t = threadIdx.x;
    const int which = blockIdx.y;   // 0=Q, 1=K, 2=V
    const float* bias = (which == 0) ? bq : (which == 1) ? bk : bv;
    const unsigned short* Wg = WtB + which * 16384;

    const int wave = t >> 6, lane = t & 63;
    const int quad = lane >> 4, li = lane & 15;
    const int m0 = blockIdx.x * 64 + wave * 16;
    int mrow = m0 + li;
    if (mrow >= n_nodes) mrow = n_nodes - 1;     // clamp; stores guarded

    f32x4 acc[8];
#pragma unroll
    for (int nt = 0; nt < 8; ++nt) acc[nt] = (f32x4){0.f, 0.f, 0.f, 0.f};

#pragma unroll
    for (int ks = 0; ks < 4; ++ks) {
        const float4* xr = (const float4*)(X + (size_t)mrow * 128 + ks * 32 + quad * 8);
        const float4 x0 = xr[0], x1 = xr[1];
        bf16x8 a;
        a[0] = (short)f2bf(x0.x); a[1] = (short)f2bf(x0.y);
        a[2] = (short)f2bf(x0.z); a[3] = (short)f2bf(x0.w);
        a[4] = (short)f2bf(x1.x); a[5] = (short)f2bf(x1.y);
        a[6] = (short)f2bf(x1.z); a[7] = (short)f2bf(x1.w);
#pragma unroll
        for (int nt = 0; nt < 8; ++nt) {
            const bf16x8 b = *(const bf16x8*)(Wg + (nt * 16 + li) * 128 + ks * 32 + quad * 8);
            acc[nt] = __builtin_amdgcn_mfma_f32_16x16x32_bf16(a, b, acc[nt], 0, 0, 0);
        }
    }

    // bias + pack (D: row = quad*4+r, col = nt*16+li)
#pragma unroll
    for (int nt = 0; nt < 8; ++nt) {
        const float bb = bias[nt * 16 + li];
#pragma unroll
        for (int r = 0; r < 4; ++r)
            stg[wave][quad * 4 + r][nt * 16 + li] = f2bf(acc[nt][r] + bb);
    }
    __syncthreads();

    // readback: 4 lanes per row, 64B chunks, coalesced vec stores
    {
        const int R = lane >> 2;
        const int c = lane & 3;
        const int node = m0 + R;
        if (node < n_nodes) {
            const uint4* s = (const uint4*)(&stg[wave][R][c * 32]);
            uint4 d0 = s[0], d1 = s[1], d2 = s[2], d3 = s[3];
            unsigned short* dp =
                (which == 0) ? (QVb + (size_t)node * 256 + c * 32)
              : (which == 1) ? (Kb  + (size_t)node * 128 + c * 32)
              :                (QVb + (size_t)node * 256 + 128 + c * 32);
            uint4* d = (uint4*)dp;
            d[0] = d0; d[1] = d1; d[2] = d2; d[3] = d3;
        }
    }
}

// ---------------------------------------------------------------------------
// 3-phase scan over counts
// ---------------------------------------------------------------------------
__global__ __launch_bounds__(256) void scan1_kernel(
    const int* __restrict__ counts, int* __restrict__ bsums, int n)
{
    __shared__ int lds[256];
    const int i = blockIdx.x * 256 + threadIdx.x;
    lds[threadIdx.x] = (i < n) ? counts[i] : 0;
    __syncthreads();
    for (int off = 128; off > 0; off >>= 1) {
        if (threadIdx.x < off) lds[threadIdx.x] += lds[threadIdx.x + off];
        __syncthreads();
    }
    if (threadIdx.x == 0) bsums[blockIdx.x] = lds[0];
}

__global__ __launch_bounds__(256) void scan2_kernel(int* __restrict__ bsums, int nb)
{
    __shared__ int lds[256];
    const int t = threadIdx.x;
    const int v = (t < nb) ? bsums[t] : 0;
    lds[t] = v;
    __syncthreads();
    for (int off = 1; off < 256; off <<= 1) {
        const int u = (t >= off) ? lds[t - off] : 0;
        __syncthreads();
        lds[t] += u;
        __syncthreads();
    }
    if (t < nb) bsums[t] = lds[t] - v;   // exclusive
}

__global__ __launch_bounds__(256) void scan3_kernel(
    const int* __restrict__ counts, const int* __restrict__ bsums,
    int* __restrict__ offsets, int* __restrict__ cursor, int n, int n_edges)
{
    __shared__ int lds[256];
    const int t = threadIdx.x;
    const int i = blockIdx.x * 256 + t;
    const int v = (i < n) ? counts[i] : 0;
    lds[t] = v;
    __syncthreads();
    for (int off = 1; off < 256; off <<= 1) {
        const int u = (t >= off) ? lds[t - off] : 0;
        __syncthreads();
        lds[t] += u;
        __syncthreads();
    }
    if (i < n) {
        const int excl = bsums[blockIdx.x] + lds[t] - v;
        offsets[i] = excl;
        cursor[i]  = excl;
    }
    if (blockIdx.x == 0 && t == 0) offsets[n] = n_edges;
}

// ---------------------------------------------------------------------------
// scatter: src ids + per-edge 8-head bias (bf16) into dst-sorted order
// ---------------------------------------------------------------------------
__global__ __launch_bounds__(256) void scatter_kernel(
    const int* __restrict__ el, const float* __restrict__ ef,
    const float* __restrict__ WeR, const float* __restrict__ beR,
    int* __restrict__ cursor, int* __restrict__ srcs,
    unsigned short* __restrict__ ebias, int n_edges)
{
    __shared__ float WeRs[EDGE_DIM * NUM_HEADS];
    __shared__ float beRs[NUM_HEADS];
    const int t = threadIdx.x;
    WeRs[t] = WeR[t];
    if (t < NUM_HEADS) beRs[t] = beR[t];
    __syncthreads();

    const int e = blockIdx.x * 256 + t;
    if (e >= n_edges) return;
    const int2 ed = ((const int2*)el)[e];
    const int src = ed.x, dst = ed.y;

    float acc[NUM_HEADS];
#pragma unroll
    for (int h = 0; h < NUM_HEADS; ++h) acc[h] = beRs[h];

    const float4* efr = (const float4*)(ef + (size_t)e * EDGE_DIM);
#pragma unroll
    for (int kk = 0; kk < 8; ++kk) {
        const float4 f = efr[kk];
        const float* w0 = &WeRs[(kk * 4 + 0) * NUM_HEADS];
        const float* w1 = &WeRs[(kk * 4 + 1) * NUM_HEADS];
        const float* w2 = &WeRs[(kk * 4 + 2) * NUM_HEADS];
        const float* w3 = &WeRs[(kk * 4 + 3) * NUM_HEADS];
#pragma unroll
        for (int h = 0; h < NUM_HEADS; ++h)
            acc[h] = fmaf(f.x, w0[h], fmaf(f.y, w1[h], fmaf(f.z, w2[h], fmaf(f.w, w3[h], acc[h]))));
    }

    const int pos = atomicAdd(&cursor[dst], 1);
    srcs[pos] = src;
    uint4 pk;
    pk.x = (unsigned)f2bf(acc[0]) | ((unsigned)f2bf(acc[1]) << 16);
    pk.y = (unsigned)f2bf(acc[2]) | ((unsigned)f2bf(acc[3]) << 16);
    pk.z = (unsigned)f2bf(acc[4]) | ((unsigned)f2bf(acc[5]) << 16);
    pk.w = (unsigned)f2bf(acc[6]) | ((unsigned)f2bf(acc[7]) << 16);
    *(uint4*)(ebias + (size_t)pos * NUM_HEADS) = pk;
}

// ---------------------------------------------------------------------------
// aggregate: 2 edges per wave (32 lanes/edge, 4 elems/lane).
// lane = half*32 + ln;  node = 2*wave + half;  h = ln>>2, j = ln&3.
// ---------------------------------------------------------------------------
__global__ __launch_bounds__(256) void aggregate_kernel(
    const unsigned short* __restrict__ QVb, const unsigned short* __restrict__ Kb,
    const int* __restrict__ offsets, const int* __restrict__ srcs,
    const unsigned short* __restrict__ ebias,
    float* __restrict__ out, int n_nodes)
{
    const int gw   = (blockIdx.x * 256 + threadIdx.x) >> 6;
    const int lane = threadIdx.x & 63;
    const int half = lane >> 5, ln = lane & 31;
    const int node = gw * 2 + half;
    const int h = ln >> 2;
    const bool valid = node < n_nodes;

    int beg = 0, end = 0;
    if (valid) { beg = offsets[node]; end = offsets[node + 1]; }
    const int cnt = end - beg;
    const int mcnt = max(cnt, __shfl_xor(cnt, 32));

    float k0 = 0.f, k1 = 0.f, k2 = 0.f, k3 = 0.f;
    if (valid) {
        const uint2 kp = ((const uint2*)(Kb + (size_t)node * 128))[ln];
        k0 = bflo(kp.x); k1 = bfhi(kp.x); k2 = bflo(kp.y); k3 = bfhi(kp.y);
    }

    float a0 = 0.f, a1 = 0.f, a2 = 0.f, a3 = 0.f;

    uint2 qp = make_uint2(0, 0), vp = make_uint2(0, 0);
    float eb = 0.f;
    if (cnt > 0) {
        const int src = srcs[beg];
        const uint2* r = (const uint2*)(QVb + (size_t)src * 256);
        qp = r[ln];
        vp = r[32 + ln];
        eb = bflo((unsigned)ebias[(size_t)beg * NUM_HEADS + h]);
    }

    for (int i = 0; i < mcnt; ++i) {
        uint2 nqp = qp, nvp = vp;
        float neb = eb;
        if (i + 1 < cnt) {   // prefetch next edge (half-uniform branch)
            const int ns = srcs[beg + i + 1];
            const uint2* r = (const uint2*)(QVb + (size_t)ns * 256);
            nqp = r[ln];
            nvp = r[32 + ln];
            neb = bflo((unsigned)ebias[(size_t)(beg + i + 1) * NUM_HEADS + h]);
        }

        const float q0 = bflo(qp.x), q1 = bfhi(qp.x);
        const float q2 = bflo(qp.y), q3 = bfhi(qp.y);
        float p = fmaf(q0, k0, fmaf(q1, k1, fmaf(q2, k2, q3 * k3)));
        p += __shfl_xor(p, 1);
        p += __shfl_xor(p, 2);
        const float score = fmaf(p, SCALE, eb);

        float mx = score;
        mx = fmaxf(mx, __shfl_xor(mx, 4));
        mx = fmaxf(mx, __shfl_xor(mx, 8));
        mx = fmaxf(mx, __shfl_xor(mx, 16));
        const float ex = __expf(score - mx);
        float den = ex;
        den += __shfl_xor(den, 4);
        den += __shfl_xor(den, 8);
        den += __shfl_xor(den, 16);
        const float w = __fdividef(ex, den);

        if (i < cnt) {   // half-uniform branch
            a0 = fmaf(w, bflo(vp.x), a0);
            a1 = fmaf(w, bfhi(vp.x), a1);
            a2 = fmaf(w, bflo(vp.y), a2);
            a3 = fmaf(w, bfhi(vp.y), a3);
        }
        qp = nqp; vp = nvp; eb = neb;
    }

    if (valid)
        ((float4*)(out + (size_t)node * OUT_DIM))[ln] = make_float4(a0, a1, a2, a3);
}

// ---------------------------------------------------------------------------
extern "C" void kernel_launch(void* const* d_in, const int* in_sizes, int n_in,
                              void* d_out, int out_size, void* d_ws, size_t ws_size,
                              hipStream_t stream)
{
    const float* X   = (const float*)d_in[0];
    const float* ef  = (const float*)d_in[1];
    const float* Wq  = (const float*)d_in[2];
    const float* bq  = (const float*)d_in[3];
    const float* Wk  = (const float*)d_in[4];
    const float* bk  = (const float*)d_in[5];
    const float* Wv  = (const float*)d_in[6];
    const float* bv  = (const float*)d_in[7];
    const float* We  = (const float*)d_in[8];
    const float* be  = (const float*)d_in[9];
    const int*   el  = (const int*)d_in[10];

    const int n_nodes = in_sizes[0] / IN_DIM;
    const int n_edges = in_sizes[10] / 2;

    char* w = (char*)d_ws;
    auto alloc = [&](size_t bytes) { char* p = w; w += (bytes + 255) & ~(size_t)255; return p; };

    unsigned short* QVb   = (unsigned short*)alloc((size_t)n_nodes * 256 * 2);
    unsigned short* Kb    = (unsigned short*)alloc((size_t)n_nodes * 128 * 2);
    unsigned short* WtB   = (unsigned short*)alloc((size_t)3 * 128 * 128 * 2);
    unsigned short* ebias = (unsigned short*)alloc((size_t)n_edges * NUM_HEADS * 2);
    float* WeR   = (float*)alloc(EDGE_DIM * NUM_HEADS * 4);
    float* beR   = (float*)alloc(NUM_HEADS * 4);
    int* counts  = (int*)alloc((size_t)n_nodes * 4);
    int* offsets = (int*)alloc((size_t)(n_nodes + 1) * 4);
    int* cursor  = (int*)alloc((size_t)n_nodes * 4);
    int* srcs    = (int*)alloc((size_t)n_edges * 4);
    int* bsums   = (int*)alloc(256 * 4);

    hipMemsetAsync(counts, 0, (size_t)n_nodes * sizeof(int), stream);

    const int nbh = (n_edges + 255) / 256;
    const int nbw = (3 * 128 * 128) / 256;
    prep_kernel<<<nbh + nbw + 1, 256, 0, stream>>>(
        el, counts, n_edges, nbh, Wq, Wk, Wv, WtB, nbw, We, be, WeR, beR);

    dim3 qkv_grid((n_nodes + 63) / 64, 3);
    qkv_mfma_kernel<<<qkv_grid, 256, 0, stream>>>(X, WtB, bq, bk, bv, QVb, Kb, n_nodes);

    const int nb = (n_nodes + 255) / 256;
    scan1_kernel<<<nb, 256, 0, stream>>>(counts, bsums, n_nodes);
    scan2_kernel<<<1, 256, 0, stream>>>(bsums, nb);
    scan3_kernel<<<nb, 256, 0, stream>>>(counts, bsums, offsets, cursor, n_nodes, n_edges);

    scatter_kernel<<<(n_edges + 255) / 256, 256, 0, stream>>>(
        el, ef, WeR, beR, cursor, srcs, ebias, n_edges);

    const int nwaves = (n_nodes + 1) / 2;
    aggregate_kernel<<<(nwaves * 64 + 255) / 256, 256, 0, stream>>>(
        QVb, Kb, offsets, srcs, ebias, (float*)d_out, n_nodes);
}